// Round 8
// baseline (248.199 us; speedup 1.0000x reference)
//
#include <hip/hip_runtime.h>
#include <hip/hip_bf16.h>
#include <math.h>

#define NB 8
#define CC 512
#define HH 64
#define WW 64
#define GG 16
#define GCH 32
#define OO 32                      // 2*G offset rows
#define XROW 520                   // LDS x1 row stride in bf16 (1040 B -> balanced bank groups)

__device__ __forceinline__ float gelu_exact(float x) {
    return 0.5f * x * (1.0f + erff(x * 0.70710678118654752f));
}

__device__ __forceinline__ unsigned pack_bf2(float a, float b) {
    __hip_bfloat162 t = __float22bfloat162_rn(make_float2(a, b));
    return *(unsigned*)&t;
}

typedef __attribute__((ext_vector_type(8))) short bf16x8;
typedef __attribute__((ext_vector_type(4))) float f32x4;

// ============================================================================
// ONE kernel: dwconv3x3 + LN + GELU + offset-GEMM + bilinear sample + NCHW out.
// Round-7 lessons: (a) param-LDS staging REGRESSED (-12us) -> reverted to the
// proven r6 conv (84.8us). (b) The coords dependency is block-local: sample
// row h needs only block (n,h)'s GEMM output -> full fusion. coords live in
// LDS only; the coords workspace, the second launch, and the global
// kernel1->kernel2 barrier all disappear.
// Phases per block (n, h, 32-px half-row), 512 threads:
//   conv(4px x 8ch, float4+shfl, XCD-swizzled n) -> LN stats -> GELU -> xbuf
//   -> GEMM (waves 0-3, px/py -> LDS) -> sample 4 passes x 4 groups
//   (8 float4 gathers in flight/thread) -> LDS transpose (aliases dead xbuf)
//   -> nontemporal NCHW stores.
// LDS: xbuf 33280 (aliased: redS head 2KB in conv phase; smem[4][32][33]
// 16.9KB in sample phase) + pxy 4KB + mu/rs 256B = 37.6KB -> 4 blocks/CU.
// ============================================================================
__global__ __launch_bounds__(512, 4)
void fused_all_kernel(const float* __restrict__ in_first,
                      const float* __restrict__ in_last,
                      const float* __restrict__ dw_w,
                      const float* __restrict__ dw_b,
                      const float* __restrict__ ln_g,
                      const float* __restrict__ ln_b,
                      const float* __restrict__ off_w,
                      const float* __restrict__ off_b,
                      float* __restrict__ out)
{
    // XCD swizzle: 1024 blocks, bid%8 = XCD -> XCD k runs image n=k.
    const int bid = blockIdx.x;
    const int nb  = (bid & 7) * 128 + (bid >> 3);
    const int n   = nb >> 7;
    const int h   = (nb & 127) >> 1;
    const int w0  = (nb & 1) * 32;    // this block's 32-px half-row

    const int tid  = threadIdx.x;
    const int wq   = tid & 7;         // 8 groups of 4 px
    const int cgrp = tid >> 3;        // 64 groups of 8 channels
    const int wb   = wq * 4;          // local px base (0..28)
    const int c0   = cgrp * 8;
    const int wave = tid >> 6;        // 8 waves
    const int lane = tid & 63;

    __shared__ short xbuf[32 * XROW];   // 33280 B (aliased: redS head / smem later)
    __shared__ float mu_s[32];
    __shared__ float rs_s[32];
    __shared__ float pxs_l[GG][32];     // sampling coords, LDS-only
    __shared__ float pys_l[GG][32];
    float* redS  = (float*)xbuf;        // [8][32] partial sums (dead before xbuf written)
    float* redS2 = (float*)xbuf + 256;

    // ---------- depthwise 3x3 conv + bias (r6 proven: float4 + shfl halo) ----------
    float xv[4][8];                     // fully-unrolled static accesses only
    float sw[4] = {0.f, 0.f, 0.f, 0.f};
    float sq[4] = {0.f, 0.f, 0.f, 0.f};

    const float* inbase = in_first + ((size_t)n * CC + c0) * HH * WW;

    #pragma unroll
    for (int i = 0; i < 8; ++i) {
        const int c = c0 + i;
        float w9[9];
        #pragma unroll
        for (int k = 0; k < 9; ++k) w9[k] = dw_w[c * 9 + k];
        const float b = dw_b[c];
        float a0 = b, a1 = b, a2 = b, a3 = b;
        #pragma unroll
        for (int r = 0; r < 3; ++r) {
            const int y = h + r - 1;
            if (y < 0 || y >= HH) continue;           // uniform across block
            const float* rowp0 = inbase + ((size_t)i * HH + y) * WW + w0;
            const float4 m = *(const float4*)(rowp0 + wb);
            float left  = __shfl_up(m.w, 1);    // lane-1 is wq-1 same cgrp (interior)
            float right = __shfl_down(m.x, 1);  // lane+1 is wq+1 same cgrp (interior)
            if (wq == 0) left  = (w0 > 0)       ? rowp0[-1] : 0.0f;
            if (wq == 7) right = (w0 + 32 < WW) ? rowp0[32] : 0.0f;
            const float k0 = w9[r * 3 + 0], k1 = w9[r * 3 + 1], k2 = w9[r * 3 + 2];
            a0 += k0 * left + k1 * m.x + k2 * m.y;
            a1 += k0 * m.x  + k1 * m.y + k2 * m.z;
            a2 += k0 * m.y  + k1 * m.z + k2 * m.w;
            a3 += k0 * m.z  + k1 * m.w + k2 * right;
        }
        xv[0][i] = a0; xv[1][i] = a1; xv[2][i] = a2; xv[3][i] = a3;
        sw[0] += a0; sq[0] += a0 * a0;
        sw[1] += a1; sq[1] += a1 * a1;
        sw[2] += a2; sq[2] += a2 * a2;
        sw[3] += a3; sq[3] += a3 * a3;
    }

    // ---------- LayerNorm stats ----------
    #pragma unroll
    for (int j = 0; j < 4; ++j) {
        sw[j] += __shfl_xor(sw[j], 8);  sq[j] += __shfl_xor(sq[j], 8);
        sw[j] += __shfl_xor(sw[j], 16); sq[j] += __shfl_xor(sq[j], 16);
        sw[j] += __shfl_xor(sw[j], 32); sq[j] += __shfl_xor(sq[j], 32);
    }
    if (lane < 8) {
        #pragma unroll
        for (int j = 0; j < 4; ++j) {
            redS [wave * 32 + wb + j] = sw[j];
            redS2[wave * 32 + wb + j] = sq[j];
        }
    }
    __syncthreads();
    if (tid < 32) {
        float s = 0.f, s2 = 0.f;
        #pragma unroll
        for (int k = 0; k < 8; ++k) {
            s  += redS [k * 32 + tid];
            s2 += redS2[k * 32 + tid];
        }
        const float mu  = s * (1.0f / 512.0f);
        const float var = s2 * (1.0f / 512.0f) - mu * mu;
        mu_s[tid] = mu;
        rs_s[tid] = rsqrtf(var + 1e-6f);
    }
    __syncthreads();   // redS reads done; xbuf may now be written

    // ---------- LN affine + exact GELU + bf16 pack -> LDS x1 ----------
    {
        float mu_[4], rs_[4];
        #pragma unroll
        for (int j = 0; j < 4; ++j) { mu_[j] = mu_s[wb + j]; rs_[j] = rs_s[wb + j]; }
        unsigned pk[4][4];
        #pragma unroll
        for (int t = 0; t < 4; ++t) {           // channel pairs
            const int c = c0 + 2 * t;
            const float lgA = ln_g[c],     lbA = ln_b[c];
            const float lgB = ln_g[c + 1], lbB = ln_b[c + 1];
            #pragma unroll
            for (int j = 0; j < 4; ++j) {
                const float va = (xv[j][2 * t]     - mu_[j]) * rs_[j] * lgA + lbA;
                const float vb = (xv[j][2 * t + 1] - mu_[j]) * rs_[j] * lgB + lbB;
                pk[j][t] = pack_bf2(gelu_exact(va), gelu_exact(vb));
            }
        }
        #pragma unroll
        for (int j = 0; j < 4; ++j) {
            *(uint4*)(xbuf + (size_t)(wb + j) * XROW + c0)
                = make_uint4(pk[j][0], pk[j][1], pk[j][2], pk[j][3]);
        }
    }
    __syncthreads();

    // ---------- offset GEMM: waves 0-3, 16(px) x 16(o) tiles, K=512 -> LDS coords ----
    // C/D layout (verified m89/m91): col = lane&15, row = (lane>>4)*4 + reg.
    if (wave < 4) {
        const int ml   = lane & 15;
        const int quad = lane >> 4;
        const int pxT  = wave >> 1;
        const int oT   = wave & 1;

        const short* arow = xbuf + (size_t)(pxT * 16 + ml) * XROW + quad * 8;
        const float* brow = off_w + (size_t)(oT * 16 + ml) * CC + quad * 8;

        f32x4 acc = {0.f, 0.f, 0.f, 0.f};
        for (int k = 0; k < CC; k += 32) {
            const bf16x8 af = *(const bf16x8*)(arow + k);
            const float4 p = *(const float4*)(brow + k);
            const float4 q = *(const float4*)(brow + k + 4);
            union { bf16x8 v; unsigned u[4]; } bb;
            bb.u[0] = pack_bf2(p.x, p.y); bb.u[1] = pack_bf2(p.z, p.w);
            bb.u[2] = pack_bf2(q.x, q.y); bb.u[3] = pack_bf2(q.z, q.w);
            acc = __builtin_amdgcn_mfma_f32_16x16x32_bf16(af, bb.v, acc, 0, 0, 0);
        }

        const int   o   = oT * 16 + ml;
        const float ob  = off_b[o];
        const int   par = o & 1;            // even o -> x-offset, odd -> y-offset
        const int   g   = o >> 1;
        float* dst = par ? &pys_l[0][0] : &pxs_l[0][0];
        #pragma unroll
        for (int r = 0; r < 4; ++r) {
            const int wl = pxT * 16 + quad * 4 + r;
            const float base = par ? (float)h : (float)(w0 + wl);
            dst[g * 32 + wl] = base + acc[r] + ob;
        }
    }
    __syncthreads();   // coords ready; xbuf (GEMM A) dead -> smem may alias

    // ---------- bilinear sample + NCHW store: 4 passes x 4 groups ----------
    float* smem = (float*)xbuf;        // [4*32 rows][33] floats, 16.9 KB
    const int g4  = tid >> 7;          // 0..3   group-within-pass
    const int spx = (tid >> 2) & 31;   // 0..31  px
    const int sc4 = tid & 3;           // 0..3   8-ch slice
    const int cl  = tid >> 2;          // 0..127 store: c-local
    const int q   = tid & 3;           // 0..3   store: 8-px quarter
    const float* sbase = in_last + (size_t)n * HH * WW * CC;

    for (int gp = 0; gp < 4; ++gp) {
        const int g = gp * 4 + g4;
        const float ppx = pxs_l[g][spx];
        const float ppy = pys_l[g][spx];
        const float x0f = floorf(ppx), y0f = floorf(ppy);
        const float fx = ppx - x0f, fy = ppy - y0f;
        const int x0 = (int)x0f, y0 = (int)y0f;

        int   off[4];
        float wt [4];
        #pragma unroll
        for (int t = 0; t < 4; ++t) {
            const int xi = x0 + (t & 1);
            const int yi = y0 + (t >> 1);
            const int xc = min(max(xi, 0), WW - 1);
            const int yc = min(max(yi, 0), HH - 1);
            const float valid = (xi >= 0 && xi < WW && yi >= 0 && yi < HH) ? 1.0f : 0.0f;
            wt [t] = ((t & 1) ? fx : 1.0f - fx) * ((t >> 1) ? fy : 1.0f - fy) * valid;
            off[t] = (yc * WW + xc) * CC;
        }
        const float* tb = sbase + g * GCH + sc4 * 8;
        float4 v[8];
        #pragma unroll
        for (int t = 0; t < 4; ++t) {         // 8 independent loads in flight
            v[2 * t]     = *(const float4*)(tb + off[t]);
            v[2 * t + 1] = *(const float4*)(tb + off[t] + 4);
        }
        float a[8] = {0.f, 0.f, 0.f, 0.f, 0.f, 0.f, 0.f, 0.f};
        #pragma unroll
        for (int t = 0; t < 4; ++t) {
            a[0] += wt[t] * v[2 * t].x;     a[1] += wt[t] * v[2 * t].y;
            a[2] += wt[t] * v[2 * t].z;     a[3] += wt[t] * v[2 * t].w;
            a[4] += wt[t] * v[2 * t + 1].x; a[5] += wt[t] * v[2 * t + 1].y;
            a[6] += wt[t] * v[2 * t + 1].z; a[7] += wt[t] * v[2 * t + 1].w;
        }
        __syncthreads();                      // prev pass smem reads done
        {
            const int row = g4 * 32 + spx;
            #pragma unroll
            for (int j = 0; j < 8; ++j) smem[row * 33 + sc4 * 8 + j] = a[j];
        }
        __syncthreads();
        {
            const int g4r = cl >> 5;
            const int cin = cl & 31;
            const int c   = (gp * 4 + g4r) * GCH + cin;
            float o[8];
            #pragma unroll
            for (int j = 0; j < 8; ++j) o[j] = smem[(g4r * 32 + q * 8 + j) * 33 + cin];
            f32x4 o1 = {o[0], o[1], o[2], o[3]};
            f32x4 o2 = {o[4], o[5], o[6], o[7]};
            float* op = out + (((size_t)n * CC + c) * HH + h) * WW + w0 + q * 8;
            __builtin_nontemporal_store(o1, (f32x4*)op);
            __builtin_nontemporal_store(o2, (f32x4*)(op + 4));
        }
    }
}

extern "C" void kernel_launch(void* const* d_in, const int* in_sizes, int n_in,
                              void* d_out, int out_size, void* d_ws, size_t ws_size,
                              hipStream_t stream) {
    const float* in_first = (const float*)d_in[0];
    const float* in_last  = (const float*)d_in[1];
    const float* dw_w     = (const float*)d_in[2];
    const float* dw_b     = (const float*)d_in[3];
    const float* ln_g     = (const float*)d_in[4];
    const float* ln_b     = (const float*)d_in[5];
    const float* off_w    = (const float*)d_in[6];
    const float* off_b    = (const float*)d_in[7];
    float* out = (float*)d_out;
    (void)d_ws; (void)ws_size;          // coords never leave LDS anymore

    fused_all_kernel<<<HH * 2 * NB, 512, 0, stream>>>(
        in_first, in_last, dw_w, dw_b, ln_g, ln_b, off_w, off_b, out);
}

// Round 9
// 245.361 us; speedup vs baseline: 1.0116x; 1.0116x over previous
//
#include <hip/hip_runtime.h>
#include <hip/hip_bf16.h>
#include <math.h>

#define NB 8
#define CC 512
#define HH 64
#define WW 64
#define GG 16
#define GCH 32
#define OO 32                      // 2*G offset rows
#define XROW 520                   // LDS x1 row stride in bf16 (1040 B -> balanced bank groups)

__device__ __forceinline__ float gelu_exact(float x) {
    return 0.5f * x * (1.0f + erff(x * 0.70710678118654752f));
}

__device__ __forceinline__ unsigned pack_bf2(float a, float b) {
    __hip_bfloat162 t = __float22bfloat162_rn(make_float2(a, b));
    return *(unsigned*)&t;
}

typedef __attribute__((ext_vector_type(8))) short bf16x8;
typedef __attribute__((ext_vector_type(4))) float f32x4;

// ============================================================================
// ONE kernel: dwconv3x3 + LN + GELU + offset-GEMM + bilinear sample + NCHW out.
// Round-8 lessons: (a) nontemporal 128-B half-row stores split 256-B lines ->
// WRITE 107 MB vs 67 ideal; plain stores let same-XCD half-row partners
// combine in L2. (b) GEMM on waves 0-3 idled half the block; split-K across
// all 8 waves (partials via coord LDS + barrier). Conv/LN/GELU untouched
// (proven 56-VGPR layout, 5 configs all ~85us -> structural plateau).
// LDS: xbuf 33280 (aliased: redS head 2KB conv-phase; smem 17.4KB sample-
// phase) + pxy 4KB + mu/rs 256B = 37.9KB -> 4 blocks/CU.
// ============================================================================
__global__ __launch_bounds__(512, 4)
void fused_all_kernel(const float* __restrict__ in_first,
                      const float* __restrict__ in_last,
                      const float* __restrict__ dw_w,
                      const float* __restrict__ dw_b,
                      const float* __restrict__ ln_g,
                      const float* __restrict__ ln_b,
                      const float* __restrict__ off_w,
                      const float* __restrict__ off_b,
                      float* __restrict__ out)
{
    // XCD swizzle: 1024 blocks, bid%8 = XCD -> XCD k runs image n=k.
    const int bid = blockIdx.x;
    const int nb  = (bid & 7) * 128 + (bid >> 3);
    const int n   = nb >> 7;
    const int h   = (nb & 127) >> 1;
    const int w0  = (nb & 1) * 32;    // this block's 32-px half-row

    const int tid  = threadIdx.x;
    const int wq   = tid & 7;         // 8 groups of 4 px
    const int cgrp = tid >> 3;        // 64 groups of 8 channels
    const int wb   = wq * 4;          // local px base (0..28)
    const int c0   = cgrp * 8;
    const int wave = tid >> 6;        // 8 waves
    const int lane = tid & 63;

    __shared__ short xbuf[32 * XROW];   // 33280 B (aliased: redS head / smem later)
    __shared__ float mu_s[32];
    __shared__ float rs_s[32];
    __shared__ float pxs_l[GG][32];     // sampling coords, LDS-only
    __shared__ float pys_l[GG][32];
    float* redS  = (float*)xbuf;        // [8][32] partial sums (dead before xbuf written)
    float* redS2 = (float*)xbuf + 256;

    // ---------- depthwise 3x3 conv + bias (r6 proven: float4 + shfl halo) ----------
    float xv[4][8];                     // fully-unrolled static accesses only
    float sw[4] = {0.f, 0.f, 0.f, 0.f};
    float sq[4] = {0.f, 0.f, 0.f, 0.f};

    const float* inbase = in_first + ((size_t)n * CC + c0) * HH * WW;

    #pragma unroll
    for (int i = 0; i < 8; ++i) {
        const int c = c0 + i;
        float w9[9];
        #pragma unroll
        for (int k = 0; k < 9; ++k) w9[k] = dw_w[c * 9 + k];
        const float b = dw_b[c];
        float a0 = b, a1 = b, a2 = b, a3 = b;
        #pragma unroll
        for (int r = 0; r < 3; ++r) {
            const int y = h + r - 1;
            if (y < 0 || y >= HH) continue;           // uniform across block
            const float* rowp0 = inbase + ((size_t)i * HH + y) * WW + w0;
            const float4 m = *(const float4*)(rowp0 + wb);
            float left  = __shfl_up(m.w, 1);    // lane-1 is wq-1 same cgrp (interior)
            float right = __shfl_down(m.x, 1);  // lane+1 is wq+1 same cgrp (interior)
            if (wq == 0) left  = (w0 > 0)       ? rowp0[-1] : 0.0f;
            if (wq == 7) right = (w0 + 32 < WW) ? rowp0[32] : 0.0f;
            const float k0 = w9[r * 3 + 0], k1 = w9[r * 3 + 1], k2 = w9[r * 3 + 2];
            a0 += k0 * left + k1 * m.x + k2 * m.y;
            a1 += k0 * m.x  + k1 * m.y + k2 * m.z;
            a2 += k0 * m.y  + k1 * m.z + k2 * m.w;
            a3 += k0 * m.z  + k1 * m.w + k2 * right;
        }
        xv[0][i] = a0; xv[1][i] = a1; xv[2][i] = a2; xv[3][i] = a3;
        sw[0] += a0; sq[0] += a0 * a0;
        sw[1] += a1; sq[1] += a1 * a1;
        sw[2] += a2; sq[2] += a2 * a2;
        sw[3] += a3; sq[3] += a3 * a3;
    }

    // ---------- LayerNorm stats ----------
    #pragma unroll
    for (int j = 0; j < 4; ++j) {
        sw[j] += __shfl_xor(sw[j], 8);  sq[j] += __shfl_xor(sq[j], 8);
        sw[j] += __shfl_xor(sw[j], 16); sq[j] += __shfl_xor(sq[j], 16);
        sw[j] += __shfl_xor(sw[j], 32); sq[j] += __shfl_xor(sq[j], 32);
    }
    if (lane < 8) {
        #pragma unroll
        for (int j = 0; j < 4; ++j) {
            redS [wave * 32 + wb + j] = sw[j];
            redS2[wave * 32 + wb + j] = sq[j];
        }
    }
    __syncthreads();
    if (tid < 32) {
        float s = 0.f, s2 = 0.f;
        #pragma unroll
        for (int k = 0; k < 8; ++k) {
            s  += redS [k * 32 + tid];
            s2 += redS2[k * 32 + tid];
        }
        const float mu  = s * (1.0f / 512.0f);
        const float var = s2 * (1.0f / 512.0f) - mu * mu;
        mu_s[tid] = mu;
        rs_s[tid] = rsqrtf(var + 1e-6f);
    }
    __syncthreads();   // redS reads done; xbuf may now be written

    // ---------- LN affine + exact GELU + bf16 pack -> LDS x1 ----------
    {
        float mu_[4], rs_[4];
        #pragma unroll
        for (int j = 0; j < 4; ++j) { mu_[j] = mu_s[wb + j]; rs_[j] = rs_s[wb + j]; }
        unsigned pk[4][4];
        #pragma unroll
        for (int t = 0; t < 4; ++t) {           // channel pairs
            const int c = c0 + 2 * t;
            const float lgA = ln_g[c],     lbA = ln_b[c];
            const float lgB = ln_g[c + 1], lbB = ln_b[c + 1];
            #pragma unroll
            for (int j = 0; j < 4; ++j) {
                const float va = (xv[j][2 * t]     - mu_[j]) * rs_[j] * lgA + lbA;
                const float vb = (xv[j][2 * t + 1] - mu_[j]) * rs_[j] * lgB + lbB;
                pk[j][t] = pack_bf2(gelu_exact(va), gelu_exact(vb));
            }
        }
        #pragma unroll
        for (int j = 0; j < 4; ++j) {
            *(uint4*)(xbuf + (size_t)(wb + j) * XROW + c0)
                = make_uint4(pk[j][0], pk[j][1], pk[j][2], pk[j][3]);
        }
    }
    __syncthreads();

    // ---------- offset GEMM: ALL 8 waves, split-K (each wave K=256) ----------
    // wave = (kh<<2)|(pxT<<1)|oT. kh=1 waves write partials to pxy LDS;
    // barrier; kh=0 waves add their half + base + bias.
    // C/D layout (verified m89/m91): col = lane&15, row = (lane>>4)*4 + reg.
    {
        const int ml   = lane & 15;
        const int quad = lane >> 4;
        const int pxT  = (wave >> 1) & 1;
        const int oT   = wave & 1;
        const int kh   = wave >> 2;         // K half

        const short* arow = xbuf + (size_t)(pxT * 16 + ml) * XROW + quad * 8 + kh * 256;
        const float* brow = off_w + (size_t)(oT * 16 + ml) * CC + quad * 8 + kh * 256;

        f32x4 acc = {0.f, 0.f, 0.f, 0.f};
        #pragma unroll
        for (int k = 0; k < 256; k += 32) {
            const bf16x8 af = *(const bf16x8*)(arow + k);
            const float4 p = *(const float4*)(brow + k);
            const float4 q = *(const float4*)(brow + k + 4);
            union { bf16x8 v; unsigned u[4]; } bb;
            bb.u[0] = pack_bf2(p.x, p.y); bb.u[1] = pack_bf2(p.z, p.w);
            bb.u[2] = pack_bf2(q.x, q.y); bb.u[3] = pack_bf2(q.z, q.w);
            acc = __builtin_amdgcn_mfma_f32_16x16x32_bf16(af, bb.v, acc, 0, 0, 0);
        }

        const int   o   = oT * 16 + ml;
        const int   par = o & 1;            // even o -> x-offset, odd -> y-offset
        const int   g   = o >> 1;
        float* dst = par ? &pys_l[0][0] : &pxs_l[0][0];

        if (kh == 1) {                      // upper-half partials
            #pragma unroll
            for (int r = 0; r < 4; ++r)
                dst[g * 32 + pxT * 16 + quad * 4 + r] = acc[r];
        }
        __syncthreads();
        if (kh == 0) {                      // lower half + base + bias + partial
            const float ob = off_b[o];
            #pragma unroll
            for (int r = 0; r < 4; ++r) {
                const int wl = pxT * 16 + quad * 4 + r;
                const float base = par ? (float)h : (float)(w0 + wl);
                dst[g * 32 + wl] += base + acc[r] + ob;
            }
        }
    }
    __syncthreads();   // coords ready; xbuf (GEMM A) dead -> smem may alias

    // ---------- bilinear sample + NCHW store: 4 passes x 4 groups ----------
    float* smem = (float*)xbuf;        // [4*32 rows][33] floats, 17.4 KB
    const int g4  = tid >> 7;          // 0..3   group-within-pass
    const int spx = (tid >> 2) & 31;   // 0..31  px
    const int sc4 = tid & 3;           // 0..3   8-ch slice
    const int cl  = tid >> 2;          // 0..127 store: c-local
    const int q   = tid & 3;           // 0..3   store: 8-px quarter
    const float* sbase = in_last + (size_t)n * HH * WW * CC;

    for (int gp = 0; gp < 4; ++gp) {
        const int g = gp * 4 + g4;
        const float ppx = pxs_l[g][spx];
        const float ppy = pys_l[g][spx];
        const float x0f = floorf(ppx), y0f = floorf(ppy);
        const float fx = ppx - x0f, fy = ppy - y0f;
        const int x0 = (int)x0f, y0 = (int)y0f;

        int   off[4];
        float wt [4];
        #pragma unroll
        for (int t = 0; t < 4; ++t) {
            const int xi = x0 + (t & 1);
            const int yi = y0 + (t >> 1);
            const int xc = min(max(xi, 0), WW - 1);
            const int yc = min(max(yi, 0), HH - 1);
            const float valid = (xi >= 0 && xi < WW && yi >= 0 && yi < HH) ? 1.0f : 0.0f;
            wt [t] = ((t & 1) ? fx : 1.0f - fx) * ((t >> 1) ? fy : 1.0f - fy) * valid;
            off[t] = (yc * WW + xc) * CC;
        }
        const float* tb = sbase + g * GCH + sc4 * 8;
        float4 v[8];
        #pragma unroll
        for (int t = 0; t < 4; ++t) {         // 8 independent loads in flight
            v[2 * t]     = *(const float4*)(tb + off[t]);
            v[2 * t + 1] = *(const float4*)(tb + off[t] + 4);
        }
        float a[8] = {0.f, 0.f, 0.f, 0.f, 0.f, 0.f, 0.f, 0.f};
        #pragma unroll
        for (int t = 0; t < 4; ++t) {
            a[0] += wt[t] * v[2 * t].x;     a[1] += wt[t] * v[2 * t].y;
            a[2] += wt[t] * v[2 * t].z;     a[3] += wt[t] * v[2 * t].w;
            a[4] += wt[t] * v[2 * t + 1].x; a[5] += wt[t] * v[2 * t + 1].y;
            a[6] += wt[t] * v[2 * t + 1].z; a[7] += wt[t] * v[2 * t + 1].w;
        }
        __syncthreads();                      // prev pass smem reads done
        {
            const int row = g4 * 32 + spx;
            #pragma unroll
            for (int j = 0; j < 8; ++j) smem[row * 33 + sc4 * 8 + j] = a[j];
        }
        __syncthreads();
        {
            const int g4r = cl >> 5;
            const int cin = cl & 31;
            const int c   = (gp * 4 + g4r) * GCH + cin;
            float o[8];
            #pragma unroll
            for (int j = 0; j < 8; ++j) o[j] = smem[(g4r * 32 + q * 8 + j) * 33 + cin];
            f32x4 o1 = {o[0], o[1], o[2], o[3]};
            f32x4 o2 = {o[4], o[5], o[6], o[7]};
            float* op = out + (((size_t)n * CC + c) * HH + h) * WW + w0 + q * 8;
            *(f32x4*)op       = o1;           // plain stores: let L2 combine the
            *(f32x4*)(op + 4) = o2;           // 256-B line with the partner half-row
        }
    }
}

extern "C" void kernel_launch(void* const* d_in, const int* in_sizes, int n_in,
                              void* d_out, int out_size, void* d_ws, size_t ws_size,
                              hipStream_t stream) {
    const float* in_first = (const float*)d_in[0];
    const float* in_last  = (const float*)d_in[1];
    const float* dw_w     = (const float*)d_in[2];
    const float* dw_b     = (const float*)d_in[3];
    const float* ln_g     = (const float*)d_in[4];
    const float* ln_b     = (const float*)d_in[5];
    const float* off_w    = (const float*)d_in[6];
    const float* off_b    = (const float*)d_in[7];
    float* out = (float*)d_out;
    (void)d_ws; (void)ws_size;          // coords never leave LDS

    fused_all_kernel<<<HH * 2 * NB, 512, 0, stream>>>(
        in_first, in_last, dw_w, dw_b, ln_g, ln_b, off_w, off_b, out);
}